// Round 15
// baseline (289.414 us; speedup 1.0000x reference)
//
#include <hip/hip_runtime.h>
#include <hip/hip_bf16.h>
#include <cmath>

#define N_TOK 16384
#define D_DIM 2048
#define H_DIM 1024
#define E_DIM 64

typedef _Float16 half8 __attribute__((ext_vector_type(8)));
typedef float floatx4 __attribute__((ext_vector_type(4)));

#define GLOAD_LDS(gp, lp)                                                      \
  __builtin_amdgcn_global_load_lds(                                            \
      (const __attribute__((address_space(1))) unsigned int*)(gp),             \
      (__attribute__((address_space(3))) unsigned int*)(lp), 16, 0, 0)

// ---------------------------------------------------------------------------
// Transpose + split W1 [2048k][1024c] -> whT/wlT [1024c][2048k] f16.
// ---------------------------------------------------------------------------
__global__ __launch_bounds__(256) void splitT_w1_kernel(
    const float* __restrict__ W1, _Float16* __restrict__ whT,
    _Float16* __restrict__ wlT) {
  __shared__ float ls[64][65];
  const int k0 = blockIdx.x * 64;
  const int c0 = blockIdx.y * 64;
  const int t = threadIdx.x;
  const int tr = t >> 6;
  const int tc = t & 63;
#pragma unroll
  for (int i = 0; i < 16; i++) {
    int k = tr * 16 + i;
    ls[k][tc] = W1[(size_t)(k0 + k) * H_DIM + c0 + tc];
  }
  __syncthreads();
#pragma unroll
  for (int i = 0; i < 16; i++) {
    int c = tr * 16 + i;
    float v = ls[tc][c];
    _Float16 hv = (_Float16)v;
    _Float16 lv = (_Float16)(v - (float)hv);
    whT[(size_t)(c0 + c) * D_DIM + k0 + tc] = hv;
    wlT[(size_t)(c0 + c) * D_DIM + k0 + tc] = lv;
  }
}

// ---------------------------------------------------------------------------
// Pack + split W2 [1024k][64e] -> MFMA-B-fragment-order hi/lo f16.
// ---------------------------------------------------------------------------
__global__ __launch_bounds__(256) void pack_w2_kernel(
    const float* __restrict__ W2, _Float16* __restrict__ pW2h,
    _Float16* __restrict__ pW2l) {
  const int s = blockIdx.x;  // 32 ksteps
  const int ng = threadIdx.x >> 6;
  const int lane = threadIdx.x & 63;
  const int kg = lane >> 4, fr = lane & 15;
  half8 hh, ll;
#pragma unroll
  for (int j = 0; j < 8; j++) {
    const float v = W2[(size_t)(s * 32 + kg * 8 + j) * E_DIM + ng * 16 + fr];
    const _Float16 hv = (_Float16)v;
    hh[j] = hv;
    ll[j] = (_Float16)(v - (float)hv);
  }
  const size_t idx = (((size_t)s * 4 + ng) * 64 + lane) * 8;
  *(half8*)(pW2h + idx) = hh;
  *(half8*)(pW2l + idx) = ll;
}

// ---------------------------------------------------------------------------
// GEMM1: h = x @ W1, f16 hi/lo split, 16x16x32 MFMA (0-conflict R12 layouts),
// 256x256 tile, BK=32, 512 thr (8 waves 2Mx4N), 128KB dbuf LDS.
// R15: 4-phase/K-tile interleave with R12 register economy (single av set,
// no held-B: bh/bl re-read per phase). Staging spread across phases:
//  ph0 GLD_B_HI(T+1) | ph1 GLD_B_LO(T+1) | ph2 WRITE_A(T+1) [counted vmcnt]
//  | ph3 LOAD_A(T+2); tile end vmcnt(4) (B(T+1) landed, A(T+2) in flight).
// Each phase: {12 ds_read + stage} -> bar -> lgkm0 -> setprio+24 MFMA -> bar.
// ---------------------------------------------------------------------------
__global__ __launch_bounds__(512, 2) void gemm1_mfma_kernel(
    const float* __restrict__ x, const _Float16* __restrict__ whT,
    const _Float16* __restrict__ wlT, float* __restrict__ h) {
  extern __shared__ __align__(16) char smem[];  // 2 x 64KB: Ah|Al|Bh|Bl

  const int t = threadIdx.x;
  const int wave = t >> 6;
  const int lane = t & 63;

  const int bid = blockIdx.x;
  const int swz = (bid & 7) * 32 + (bid >> 3);  // XCD swizzle (256 = 8*32)
  const int by = swz >> 2, bx = swz & 3;
  const int row0 = by * 256, col0 = bx * 256;
  const int wr = wave >> 2, wc = wave & 3;  // wave tile 128x64

  floatx4 acc[8][4];
#pragma unroll
  for (int m = 0; m < 8; m++)
#pragma unroll
    for (int n = 0; n < 4; n++) acc[m][n] = (floatx4){0.f, 0.f, 0.f, 0.f};

  int awaddr[2];
  size_t gaoff[2];
#pragma unroll
  for (int q = 0; q < 2; q++) {
    const int u = q * 512 + t;
    const int arow = u >> 2;
    const int aslot = u & 3;
    awaddr[q] = arow * 64 + ((aslot ^ ((arow >> 1) & 3)) << 4);
    gaoff[q] = (size_t)(row0 + arow) * D_DIM + aslot * 8;
  }

  int ldsoff[2];
  size_t gboff[2];
#pragma unroll
  for (int q = 0; q < 2; q++) {
    const int o = q * 8192 + t * 16;
    const int row = o >> 6;
    const int ss = ((o >> 4) & 3) ^ ((row >> 1) & 3);
    ldsoff[q] = q * 8192 + wave * 1024;
    gboff[q] = (size_t)(col0 + row) * D_DIM + ss * 8;
  }

  const int kg = lane >> 4;
  const int fr = lane & 15;

  int afr[8], bfr[4];
#pragma unroll
  for (int m = 0; m < 8; m++) {
    const int r = wr * 128 + m * 16 + fr;
    afr[m] = r * 64 + ((kg ^ ((r >> 1) & 3)) << 4);
  }
#pragma unroll
  for (int n = 0; n < 4; n++) {
    const int c = wc * 64 + n * 16 + fr;
    bfr[n] = c * 64 + ((kg ^ ((c >> 1) & 3)) << 4);
  }

  float4 av[2][2];

#define LOAD_A(T)                                                              \
  do {                                                                         \
    const size_t kk = (size_t)(T) * 32;                                        \
    av[0][0] = *(const float4*)(x + gaoff[0] + kk);                            \
    av[0][1] = *(const float4*)(x + gaoff[0] + kk + 4);                        \
    av[1][0] = *(const float4*)(x + gaoff[1] + kk);                            \
    av[1][1] = *(const float4*)(x + gaoff[1] + kk + 4);                        \
  } while (0)

#define WRITE_A(B)                                                             \
  do {                                                                         \
    char* lb = smem + (B) * 65536;                                             \
    _Pragma("unroll") for (int q = 0; q < 2; q++) {                            \
      float vs[8] = {av[q][0].x, av[q][0].y, av[q][0].z, av[q][0].w,           \
                     av[q][1].x, av[q][1].y, av[q][1].z, av[q][1].w};          \
      half8 hh, ll;                                                            \
      _Pragma("unroll") for (int j = 0; j < 8; j++) {                          \
        _Float16 hv = (_Float16)vs[j];                                         \
        hh[j] = hv;                                                            \
        ll[j] = (_Float16)(vs[j] - (float)hv);                                 \
      }                                                                        \
      *(half8*)(lb + awaddr[q]) = hh;                                          \
      *(half8*)(lb + 16384 + awaddr[q]) = ll;                                  \
    }                                                                          \
  } while (0)

#define GLD_B_HI(T)                                                            \
  do {                                                                         \
    const size_t kk = (size_t)(T) * 32;                                        \
    char* db = smem + ((T) & 1) * 65536;                                       \
    GLOAD_LDS(whT + gboff[0] + kk, db + 32768 + ldsoff[0]);                    \
    GLOAD_LDS(whT + gboff[1] + kk, db + 32768 + ldsoff[1]);                    \
  } while (0)

#define GLD_B_LO(T)                                                            \
  do {                                                                         \
    const size_t kk = (size_t)(T) * 32;                                        \
    char* db = smem + ((T) & 1) * 65536;                                       \
    GLOAD_LDS(wlT + gboff[0] + kk, db + 49152 + ldsoff[0]);                    \
    GLOAD_LDS(wlT + gboff[1] + kk, db + 49152 + ldsoff[1]);                    \
  } while (0)

  // One phase: 12 ds_reads (8 B + 4 A for m-pair P) + STAGE, bar, lgkm0,
  // setprio + 24 MFMA + setprio0, bar (END controls the trailing sync).
#define PHASE(P, STAGE, END)                                                   \
  do {                                                                         \
    half8 bh0 = *(const half8*)(cb + 32768 + bfr[0]);                          \
    half8 bl0 = *(const half8*)(cb + 49152 + bfr[0]);                          \
    half8 bh1 = *(const half8*)(cb + 32768 + bfr[1]);                          \
    half8 bl1 = *(const half8*)(cb + 49152 + bfr[1]);                          \
    half8 bh2 = *(const half8*)(cb + 32768 + bfr[2]);                          \
    half8 bl2 = *(const half8*)(cb + 49152 + bfr[2]);                          \
    half8 bh3 = *(const half8*)(cb + 32768 + bfr[3]);                          \
    half8 bl3 = *(const half8*)(cb + 49152 + bfr[3]);                          \
    half8 ah0 = *(const half8*)(cb + afr[2 * (P)]);                            \
    half8 al0 = *(const half8*)(cb + 16384 + afr[2 * (P)]);                    \
    half8 ah1 = *(const half8*)(cb + afr[2 * (P) + 1]);                        \
    half8 al1 = *(const half8*)(cb + 16384 + afr[2 * (P) + 1]);                \
    STAGE;                                                                     \
    __builtin_amdgcn_sched_barrier(0);                                         \
    __builtin_amdgcn_s_barrier();                                              \
    asm volatile("s_waitcnt lgkmcnt(0)" ::: "memory");                         \
    __builtin_amdgcn_sched_barrier(0);                                         \
    __builtin_amdgcn_s_setprio(1);                                             \
    acc[2 * (P)][0] = __builtin_amdgcn_mfma_f32_16x16x32_f16(                  \
        ah0, bh0, acc[2 * (P)][0], 0, 0, 0);                                   \
    acc[2 * (P)][0] = __builtin_amdgcn_mfma_f32_16x16x32_f16(                  \
        ah0, bl0, acc[2 * (P)][0], 0, 0, 0);                                   \
    acc[2 * (P)][0] = __builtin_amdgcn_mfma_f32_16x16x32_f16(                  \
        al0, bh0, acc[2 * (P)][0], 0, 0, 0);                                   \
    acc[2 * (P)][1] = __builtin_amdgcn_mfma_f32_16x16x32_f16(                  \
        ah0, bh1, acc[2 * (P)][1], 0, 0, 0);                                   \
    acc[2 * (P)][1] = __builtin_amdgcn_mfma_f32_16x16x32_f16(                  \
        ah0, bl1, acc[2 * (P)][1], 0, 0, 0);                                   \
    acc[2 * (P)][1] = __builtin_amdgcn_mfma_f32_16x16x32_f16(                  \
        al0, bh1, acc[2 * (P)][1], 0, 0, 0);                                   \
    acc[2 * (P)][2] = __builtin_amdgcn_mfma_f32_16x16x32_f16(                  \
        ah0, bh2, acc[2 * (P)][2], 0, 0, 0);                                   \
    acc[2 * (P)][2] = __builtin_amdgcn_mfma_f32_16x16x32_f16(                  \
        ah0, bl2, acc[2 * (P)][2], 0, 0, 0);                                   \
    acc[2 * (P)][2] = __builtin_amdgcn_mfma_f32_16x16x32_f16(                  \
        al0, bh2, acc[2 * (P)][2], 0, 0, 0);                                   \
    acc[2 * (P)][3] = __builtin_amdgcn_mfma_f32_16x16x32_f16(                  \
        ah0, bh3, acc[2 * (P)][3], 0, 0, 0);                                   \
    acc[2 * (P)][3] = __builtin_amdgcn_mfma_f32_16x16x32_f16(                  \
        ah0, bl3, acc[2 * (P)][3], 0, 0, 0);                                   \
    acc[2 * (P)][3] = __builtin_amdgcn_mfma_f32_16x16x32_f16(                  \
        al0, bh3, acc[2 * (P)][3], 0, 0, 0);                                   \
    acc[2 * (P) + 1][0] = __builtin_amdgcn_mfma_f32_16x16x32_f16(              \
        ah1, bh0, acc[2 * (P) + 1][0], 0, 0, 0);                               \
    acc[2 * (P) + 1][0] = __builtin_amdgcn_mfma_f32_16x16x32_f16(              \
        ah1, bl0, acc[2 * (P) + 1][0], 0, 0, 0);                               \
    acc[2 * (P) + 1][0] = __builtin_amdgcn_mfma_f32_16x16x32_f16(              \
        al1, bh0, acc[2 * (P) + 1][0], 0, 0, 0);                               \
    acc[2 * (P) + 1][1] = __builtin_amdgcn_mfma_f32_16x16x32_f16(              \
        ah1, bh1, acc[2 * (P) + 1][1], 0, 0, 0);                               \
    acc[2 * (P) + 1][1] = __builtin_amdgcn_mfma_f32_16x16x32_f16(              \
        ah1, bl1, acc[2 * (P) + 1][1], 0, 0, 0);                               \
    acc[2 * (P) + 1][1] = __builtin_amdgcn_mfma_f32_16x16x32_f16(              \
        al1, bh1, acc[2 * (P) + 1][1], 0, 0, 0);                               \
    acc[2 * (P) + 1][2] = __builtin_amdgcn_mfma_f32_16x16x32_f16(              \
        ah1, bh2, acc[2 * (P) + 1][2], 0, 0, 0);                               \
    acc[2 * (P) + 1][2] = __builtin_amdgcn_mfma_f32_16x16x32_f16(              \
        ah1, bl2, acc[2 * (P) + 1][2], 0, 0, 0);                               \
    acc[2 * (P) + 1][2] = __builtin_amdgcn_mfma_f32_16x16x32_f16(              \
        al1, bh2, acc[2 * (P) + 1][2], 0, 0, 0);                               \
    acc[2 * (P) + 1][3] = __builtin_amdgcn_mfma_f32_16x16x32_f16(              \
        ah1, bh3, acc[2 * (P) + 1][3], 0, 0, 0);                               \
    acc[2 * (P) + 1][3] = __builtin_amdgcn_mfma_f32_16x16x32_f16(              \
        ah1, bl3, acc[2 * (P) + 1][3], 0, 0, 0);                               \
    acc[2 * (P) + 1][3] = __builtin_amdgcn_mfma_f32_16x16x32_f16(              \
        al1, bh3, acc[2 * (P) + 1][3], 0, 0, 0);                               \
    __builtin_amdgcn_s_setprio(0);                                             \
    __builtin_amdgcn_sched_barrier(0);                                         \
    END;                                                                       \
    __builtin_amdgcn_s_barrier();                                              \
    __builtin_amdgcn_sched_barrier(0);                                         \
  } while (0)

#define NOP_STAGE do { } while (0)

  // STG: 0 steady, 1 = T=62 (no LOAD_A(T+2), drain), 2 = T=63 (tail, none)
#define BODY(T, STG)                                                           \
  do {                                                                         \
    const char* cb = smem + ((T) & 1) * 65536;                                 \
    if ((STG) < 2) {                                                           \
      PHASE(0, GLD_B_HI((T) + 1), NOP_STAGE);                                  \
      PHASE(1, GLD_B_LO((T) + 1), NOP_STAGE);                                  \
      PHASE(2, WRITE_A(((T) + 1) & 1), NOP_STAGE);                             \
      if ((STG) == 0) {                                                        \
        PHASE(3, LOAD_A((T) + 2),                                              \
              asm volatile("s_waitcnt vmcnt(4)" ::: "memory"));                \
      } else {                                                                 \
        PHASE(3, NOP_STAGE,                                                    \
              asm volatile("s_waitcnt vmcnt(0)" ::: "memory"));                \
      }                                                                        \
    } else {                                                                   \
      PHASE(0, NOP_STAGE, NOP_STAGE);                                          \
      PHASE(1, NOP_STAGE, NOP_STAGE);                                          \
      PHASE(2, NOP_STAGE, NOP_STAGE);                                          \
      PHASE(3, NOP_STAGE, NOP_STAGE);                                          \
    }                                                                          \
  } while (0)

  // ---- Prologue ----
  LOAD_A(0);
  GLD_B_HI(0);
  GLD_B_LO(0);
  WRITE_A(0);  // av wait counted: vmcnt(4) (B(0) gloads younger, in flight)
  LOAD_A(1);
  asm volatile("s_waitcnt vmcnt(4)" ::: "memory");  // B(0) landed
  asm volatile("s_waitcnt lgkmcnt(0)" ::: "memory");
  __builtin_amdgcn_s_barrier();
  __builtin_amdgcn_sched_barrier(0);

#pragma unroll 1
  for (int T = 0; T < 62; ++T) {
    BODY(T, 0);
  }
  BODY(62, 1);
  BODY(63, 2);

#undef LOAD_A
#undef WRITE_A
#undef GLD_B_HI
#undef GLD_B_LO
#undef PHASE
#undef NOP_STAGE
#undef BODY

  // Epilogue: C/D layout col=lane&15, row=(lane>>4)*4+j  [m89-verified]
  const int rj = (lane >> 4) * 4;
#pragma unroll
  for (int m = 0; m < 8; m++) {
    const int rbase = row0 + wr * 128 + m * 16 + rj;
#pragma unroll
    for (int n = 0; n < 4; n++) {
      const int c = col0 + wc * 64 + n * 16 + fr;
#pragma unroll
      for (int j = 0; j < 4; j++) {
        h[(size_t)(rbase + j) * H_DIM + c] = acc[m][n][j];
      }
    }
  }
}

// ---------------------------------------------------------------------------
// Router v2 (MFMA, R14-verified): 16 tokens/block, 256 thr (4 waves).
// ---------------------------------------------------------------------------
__device__ __forceinline__ float gelu_exact(float v) {
  return 0.5f * v * (1.0f + erff(v * 0.70710678118654752f));
}

__global__ __launch_bounds__(256) void router_kernel(
    const float* __restrict__ hbuf, const float* __restrict__ b1,
    const float* __restrict__ gamma, const float* __restrict__ beta,
    const _Float16* __restrict__ pW2h, const _Float16* __restrict__ pW2l,
    const float* __restrict__ b2, float* __restrict__ out) {
  extern __shared__ __align__(16) char rsm[];
  char* gh = rsm;                    // 32KB
  char* gl = rsm + 32768;            // 32KB
  float* lg = (float*)(rsm + 65536); // 16 x 64 fp32 = 4KB

  const int t = threadIdx.x;
  const int tok0 = blockIdx.x * 16;

  const int tk = t >> 4;
  const int l16 = t & 15;
  {
    const float* hr = hbuf + (size_t)(tok0 + tk) * H_DIM;
    float vals[64];
    float s = 0.f, s2 = 0.f;
#pragma unroll
    for (int q2 = 0; q2 < 8; q2++) {
      const int j = q2 * 128 + l16 * 8;
      float4 v0 = *(const float4*)(hr + j);
      float4 v1 = *(const float4*)(hr + j + 4);
      float4 b0 = *(const float4*)(b1 + j);
      float4 b1v = *(const float4*)(b1 + j + 4);
      v0.x += b0.x; v0.y += b0.y; v0.z += b0.z; v0.w += b0.w;
      v1.x += b1v.x; v1.y += b1v.y; v1.z += b1v.z; v1.w += b1v.w;
      vals[q2 * 8 + 0] = v0.x; vals[q2 * 8 + 1] = v0.y;
      vals[q2 * 8 + 2] = v0.z; vals[q2 * 8 + 3] = v0.w;
      vals[q2 * 8 + 4] = v1.x; vals[q2 * 8 + 5] = v1.y;
      vals[q2 * 8 + 6] = v1.z; vals[q2 * 8 + 7] = v1.w;
      s += v0.x + v0.y + v0.z + v0.w + v1.x + v1.y + v1.z + v1.w;
      s2 += v0.x * v0.x + v0.y * v0.y + v0.z * v0.z + v0.w * v0.w +
            v1.x * v1.x + v1.y * v1.y + v1.z * v1.z + v1.w * v1.w;
    }
#pragma unroll
    for (int off = 8; off; off >>= 1) {
      s += __shfl_xor(s, off, 16);
      s2 += __shfl_xor(s2, off, 16);
    }
    const float mean = s * (1.f / 1024.f);
    const float var = s2 * (1.f / 1024.f) - mean * mean;
    const float rstd = rsqrtf(var + 1e-5f);
    const int swz = ((tk >> 1) & 3);
#pragma unroll
    for (int q2 = 0; q2 < 8; q2++) {
      const int j = q2 * 128 + l16 * 8;
      half8 hh, ll;
#pragma unroll
      for (int e = 0; e < 8; e++) {
        const int jj = q2 * 8 + e;
        const int col = j + e;
        const float gm = gamma[col], bt = beta[col];
        const float gv = gelu_exact((vals[jj] - mean) * rstd * gm + bt);
        const _Float16 hv = (_Float16)gv;
        hh[e] = hv;
        ll[e] = (_Float16)(gv - (float)hv);
      }
      const int sidx = q2 * 4 + (l16 >> 2);
      const int addr = sidx * 1024 + tk * 64 + (((l16 & 3) ^ swz) << 4);
      *(half8*)(gh + addr) = hh;
      *(half8*)(gl + addr) = ll;
    }
  }
  __syncthreads();

  const int wave = t >> 6;
  const int lane = t & 63;
  const int kg = lane >> 4;
  const int fr = lane & 15;
  {
    floatx4 acc = (floatx4){0.f, 0.f, 0.f, 0.f};
    const int aswz = ((fr >> 1) & 3);
#pragma unroll
    for (int s = 0; s < 32; s++) {
      const int aaddr = s * 1024 + fr * 64 + ((kg ^ aswz) << 4);
      half8 ah = *(const half8*)(gh + aaddr);
      half8 al = *(const half8*)(gl + aaddr);
      const size_t bo = (((size_t)s * 4 + wave) * 64 + lane) * 8;
      half8 bh = *(const half8*)(pW2h + bo);
      half8 bl = *(const half8*)(pW2l + bo);
      acc = __builtin_amdgcn_mfma_f32_16x16x32_f16(ah, bh, acc, 0, 0, 0);
      acc = __builtin_amdgcn_mfma_f32_16x16x32_f16(ah, bl, acc, 0, 0, 0);
      acc = __builtin_amdgcn_mfma_f32_16x16x32_f16(al, bh, acc, 0, 0, 0);
    }
#pragma unroll
    for (int j = 0; j < 4; j++) {
      lg[(kg * 4 + j) * E_DIM + wave * 16 + fr] = acc[j];
    }
  }
  __syncthreads();

  float* out_idx = out;
  float* out_w = out + 32768;
  float* out_logits = out + 65536;

  const float b2v = b2[lane];
#pragma unroll
  for (int tt = 0; tt < 4; tt++) {
    const int tok = wave * 4 + tt;
    const int n = tok0 + tok;
    const float L = lg[tok * E_DIM + lane] + b2v;
    float m = L;
#pragma unroll
    for (int off = 32; off; off >>= 1) m = fmaxf(m, __shfl_xor(m, off));
    const float ex = expf(L - m);
    float sum = ex;
#pragma unroll
    for (int off = 32; off; off >>= 1) sum += __shfl_xor(sum, off);

    float v1 = L; int i1 = lane;
#pragma unroll
    for (int off = 32; off; off >>= 1) {
      float ov = __shfl_xor(v1, off);
      int oi = __shfl_xor(i1, off);
      if (ov > v1 || (ov == v1 && oi < i1)) { v1 = ov; i1 = oi; }
    }
    float v2 = (lane == i1) ? -1e30f : L; int i2 = lane;
#pragma unroll
    for (int off = 32; off; off >>= 1) {
      float ov = __shfl_xor(v2, off);
      int oi = __shfl_xor(i2, off);
      if (ov > v2 || (ov == v2 && oi < i2)) { v2 = ov; i2 = oi; }
    }

    out_logits[(size_t)n * 64 + lane] = L;
    if (lane == 0) {
      const float p1 = expf(v1 - m) / sum;
      const float p2 = expf(v2 - m) / sum;
      const float dn = p1 + p2 + 1e-9f;
      out_idx[n * 2 + 0] = (float)i1;
      out_idx[n * 2 + 1] = (float)i2;
      out_w[n * 2 + 0] = p1 / dn;
      out_w[n * 2 + 1] = p2 / dn;
    }
  }
}

extern "C" void kernel_launch(void* const* d_in, const int* in_sizes, int n_in,
                              void* d_out, int out_size, void* d_ws, size_t ws_size,
                              hipStream_t stream) {
  const float* x = (const float*)d_in[0];
  const float* W1 = (const float*)d_in[1];
  const float* b1 = (const float*)d_in[2];
  const float* gamma = (const float*)d_in[3];
  const float* beta = (const float*)d_in[4];
  const float* W2 = (const float*)d_in[5];
  const float* b2 = (const float*)d_in[6];
  float* out = (float*)d_out;

  char* ws = (char*)d_ws;
  _Float16* whT = (_Float16*)ws;                  // 4 MiB
  _Float16* wlT = (_Float16*)(ws + 4194304);      // 4 MiB
  float* hbuf = (float*)(ws + 8388608);           // 64 MiB
  _Float16* pW2h = (_Float16*)(ws + 75497472);    // 128 KiB
  _Float16* pW2l = (_Float16*)(ws + 75628544);    // 128 KiB

  (void)hipFuncSetAttribute((const void*)gemm1_mfma_kernel,
                            hipFuncAttributeMaxDynamicSharedMemorySize,
                            131072);
  (void)hipFuncSetAttribute((const void*)router_kernel,
                            hipFuncAttributeMaxDynamicSharedMemorySize,
                            69632);

  splitT_w1_kernel<<<dim3(D_DIM / 64, H_DIM / 64), 256, 0, stream>>>(W1, whT, wlT);
  pack_w2_kernel<<<32, 256, 0, stream>>>(W2, pW2h, pW2l);

  gemm1_mfma_kernel<<<256, 512, 131072, stream>>>(x, whT, wlT, hbuf);

  router_kernel<<<N_TOK / 16, 256, 69632, stream>>>(hbuf, b1, gamma, beta,
                                                    pW2h, pW2l, b2, out);
}

// Round 16
// 265.565 us; speedup vs baseline: 1.0898x; 1.0898x over previous
//
#include <hip/hip_runtime.h>
#include <hip/hip_bf16.h>
#include <cmath>

#define N_TOK 16384
#define D_DIM 2048
#define H_DIM 1024
#define E_DIM 64

typedef _Float16 half8 __attribute__((ext_vector_type(8)));
typedef float floatx4 __attribute__((ext_vector_type(4)));

#define GLOAD_LDS(gp, lp)                                                      \
  __builtin_amdgcn_global_load_lds(                                            \
      (const __attribute__((address_space(1))) unsigned int*)(gp),             \
      (__attribute__((address_space(3))) unsigned int*)(lp), 16, 0, 0)

// ---------------------------------------------------------------------------
// Transpose + split W1 [2048k][1024c] -> whT/wlT [1024c][2048k] f16.
// ---------------------------------------------------------------------------
__global__ __launch_bounds__(256) void splitT_w1_kernel(
    const float* __restrict__ W1, _Float16* __restrict__ whT,
    _Float16* __restrict__ wlT) {
  __shared__ float ls[64][65];
  const int k0 = blockIdx.x * 64;
  const int c0 = blockIdx.y * 64;
  const int t = threadIdx.x;
  const int tr = t >> 6;
  const int tc = t & 63;
#pragma unroll
  for (int i = 0; i < 16; i++) {
    int k = tr * 16 + i;
    ls[k][tc] = W1[(size_t)(k0 + k) * H_DIM + c0 + tc];
  }
  __syncthreads();
#pragma unroll
  for (int i = 0; i < 16; i++) {
    int c = tr * 16 + i;
    float v = ls[tc][c];
    _Float16 hv = (_Float16)v;
    _Float16 lv = (_Float16)(v - (float)hv);
    whT[(size_t)(c0 + c) * D_DIM + k0 + tc] = hv;
    wlT[(size_t)(c0 + c) * D_DIM + k0 + tc] = lv;
  }
}

// ---------------------------------------------------------------------------
// Pack + split W2 [1024k][64e] -> MFMA-B-fragment-order hi/lo f16.
// ---------------------------------------------------------------------------
__global__ __launch_bounds__(256) void pack_w2_kernel(
    const float* __restrict__ W2, _Float16* __restrict__ pW2h,
    _Float16* __restrict__ pW2l) {
  const int s = blockIdx.x;  // 32 ksteps
  const int ng = threadIdx.x >> 6;
  const int lane = threadIdx.x & 63;
  const int kg = lane >> 4, fr = lane & 15;
  half8 hh, ll;
#pragma unroll
  for (int j = 0; j < 8; j++) {
    const float v = W2[(size_t)(s * 32 + kg * 8 + j) * E_DIM + ng * 16 + fr];
    const _Float16 hv = (_Float16)v;
    hh[j] = hv;
    ll[j] = (_Float16)(v - (float)hv);
  }
  const size_t idx = (((size_t)s * 4 + ng) * 64 + lane) * 8;
  *(half8*)(pW2h + idx) = hh;
  *(half8*)(pW2l + idx) = ll;
}

// ---------------------------------------------------------------------------
// GEMM1: h = x @ W1, f16 hi/lo split, 16x16x32 MFMA (0-conflict R12 layouts),
// 256x256 tile, BK=32, **1024 thr (16 waves, 4x4 grid, wave tile 64x64)**.
// acc = 4x4 frags = 64 AGPR -> ~115 total regs -> 4 waves/SIMD (vs R12's 2).
// R12's counted-vmcnt 2-barrier pipeline, per-thread ledger now vmcnt(2):
// GLD_B(T+1)[2 loads] -> MFMA -> WRITE_A(T+1)[auto-counted] -> LOAD_A(T+2)
// [2 loads] -> vmcnt(2) -> lgkmcnt(0) -> s_barrier.
// ---------------------------------------------------------------------------
__global__ __launch_bounds__(1024, 4) void gemm1_mfma_kernel(
    const float* __restrict__ x, const _Float16* __restrict__ whT,
    const _Float16* __restrict__ wlT, float* __restrict__ h) {
  extern __shared__ __align__(16) char smem[];  // 2 x 64KB: Ah|Al|Bh|Bl

  const int t = threadIdx.x;
  const int wave = t >> 6;
  const int lane = t & 63;

  const int bid = blockIdx.x;
  const int swz = (bid & 7) * 32 + (bid >> 3);  // XCD swizzle (256 = 8*32)
  const int by = swz >> 2, bx = swz & 3;
  const int row0 = by * 256, col0 = bx * 256;
  const int wr = wave >> 2, wc = wave & 3;  // 4x4 grid, wave tile 64x64

  floatx4 acc[4][4];
#pragma unroll
  for (int m = 0; m < 4; m++)
#pragma unroll
    for (int n = 0; n < 4; n++) acc[m][n] = (floatx4){0.f, 0.f, 0.f, 0.f};

  // ---- A reg-staging (R12 layout, 1 unit/thread): unit u = t ----
  const int arow = t >> 2;      // 0..255
  const int aslot = t & 3;
  const int awaddr = arow * 64 + ((aslot ^ ((arow >> 1) & 3)) << 4);
  const size_t gaoff = (size_t)(row0 + arow) * D_DIM + aslot * 8;

  // ---- B gload_lds staging (R12 layout, 1 issue per array) ----
  const int bo_ = t * 16;
  const int brow = bo_ >> 6;
  const int bss = ((bo_ >> 4) & 3) ^ ((brow >> 1) & 3);
  const int ldsBoff = wave * 1024;  // + lane*16 implicit in gload_lds
  const size_t gboff = (size_t)(col0 + brow) * D_DIM + bss * 8;

  const int kg = lane >> 4;
  const int fr = lane & 15;

  // ---- fragment ds_read offsets (R12-verified pattern, 0 conflicts) ----
  int afr[4], bfr[4];
#pragma unroll
  for (int m = 0; m < 4; m++) {
    const int r = wr * 64 + m * 16 + fr;
    afr[m] = r * 64 + ((kg ^ ((r >> 1) & 3)) << 4);
  }
#pragma unroll
  for (int n = 0; n < 4; n++) {
    const int c = wc * 64 + n * 16 + fr;
    bfr[n] = c * 64 + ((kg ^ ((c >> 1) & 3)) << 4);
  }

  float4 av0, av1;

#define LOAD_A(T)                                                              \
  do {                                                                         \
    const float* pa = x + gaoff + (size_t)(T) * 32;                            \
    av0 = *(const float4*)pa;                                                  \
    av1 = *(const float4*)(pa + 4);                                            \
  } while (0)

#define WRITE_A(B)                                                             \
  do {                                                                         \
    char* lb = smem + (B) * 65536;                                             \
    float vs[8] = {av0.x, av0.y, av0.z, av0.w, av1.x, av1.y, av1.z, av1.w};    \
    half8 hh, ll;                                                              \
    _Pragma("unroll") for (int j = 0; j < 8; j++) {                            \
      _Float16 hv = (_Float16)vs[j];                                           \
      hh[j] = hv;                                                              \
      ll[j] = (_Float16)(vs[j] - (float)hv);                                   \
    }                                                                          \
    *(half8*)(lb + awaddr) = hh;                                               \
    *(half8*)(lb + 16384 + awaddr) = ll;                                       \
  } while (0)

#define GLD_B(T)                                                               \
  do {                                                                         \
    const size_t kk = (size_t)(T) * 32;                                        \
    char* db = smem + ((T) & 1) * 65536;                                       \
    GLOAD_LDS(whT + gboff + kk, db + 32768 + ldsBoff);                         \
    GLOAD_LDS(wlT + gboff + kk, db + 49152 + ldsBoff);                         \
  } while (0)

  // STG: 0 = steady, 1 = T=62 (no LOAD_A(T+2), drain), 2 = T=63 (tail)
#define BODY(T, STG)                                                           \
  do {                                                                         \
    const char* cb = smem + ((T) & 1) * 65536;                                 \
    if ((STG) < 2) GLD_B((T) + 1);                                             \
    __builtin_amdgcn_sched_barrier(0);                                         \
    half8 bh[4], bl[4];                                                        \
    _Pragma("unroll") for (int n = 0; n < 4; n++) {                            \
      bh[n] = *(const half8*)(cb + 32768 + bfr[n]);                            \
      bl[n] = *(const half8*)(cb + 49152 + bfr[n]);                            \
    }                                                                          \
    _Pragma("unroll") for (int m = 0; m < 4; m++) {                            \
      half8 ah = *(const half8*)(cb + afr[m]);                                 \
      half8 al = *(const half8*)(cb + 16384 + afr[m]);                         \
      __builtin_amdgcn_s_setprio(1);                                           \
      _Pragma("unroll") for (int n = 0; n < 4; n++) {                          \
        acc[m][n] = __builtin_amdgcn_mfma_f32_16x16x32_f16(ah, bh[n],          \
                                                           acc[m][n], 0, 0, 0);\
        acc[m][n] = __builtin_amdgcn_mfma_f32_16x16x32_f16(ah, bl[n],          \
                                                           acc[m][n], 0, 0, 0);\
        acc[m][n] = __builtin_amdgcn_mfma_f32_16x16x32_f16(al, bh[n],          \
                                                           acc[m][n], 0, 0, 0);\
      }                                                                        \
      __builtin_amdgcn_s_setprio(0);                                           \
    }                                                                          \
    __builtin_amdgcn_sched_barrier(0);                                         \
    if ((STG) < 2) {                                                           \
      WRITE_A(((T) + 1) & 1); /* av wait auto-counted: B(T+1) in flight */     \
      if ((STG) == 0) {                                                        \
        LOAD_A((T) + 2);                                                       \
        __builtin_amdgcn_sched_barrier(0);                                     \
        asm volatile("s_waitcnt vmcnt(2)" ::: "memory"); /* B(T+1) landed */   \
      } else {                                                                 \
        __builtin_amdgcn_sched_barrier(0);                                     \
        asm volatile("s_waitcnt vmcnt(0)" ::: "memory");                       \
      }                                                                        \
      asm volatile("s_waitcnt lgkmcnt(0)" ::: "memory");                       \
      __builtin_amdgcn_s_barrier();                                            \
      __builtin_amdgcn_sched_barrier(0);                                       \
    }                                                                          \
  } while (0)

  // ---- Prologue ----
  LOAD_A(0);
  GLD_B(0);
  WRITE_A(0);  // waits A(0) regs: vmcnt(2) counted (B(0) in flight)
  LOAD_A(1);
  asm volatile("s_waitcnt vmcnt(2)" ::: "memory");  // B(0) landed, A(1) flying
  asm volatile("s_waitcnt lgkmcnt(0)" ::: "memory");
  __builtin_amdgcn_s_barrier();
  __builtin_amdgcn_sched_barrier(0);

#pragma unroll 1
  for (int T = 0; T < 62; ++T) {
    BODY(T, 0);
  }
  BODY(62, 1);
  BODY(63, 2);

#undef LOAD_A
#undef WRITE_A
#undef GLD_B
#undef BODY

  // Epilogue: C/D layout col=lane&15, row=(lane>>4)*4+j  [m89-verified]
  const int rj = (lane >> 4) * 4;
#pragma unroll
  for (int m = 0; m < 4; m++) {
    const int rbase = row0 + wr * 64 + m * 16 + rj;
#pragma unroll
    for (int n = 0; n < 4; n++) {
      const int c = col0 + wc * 64 + n * 16 + fr;
#pragma unroll
      for (int j = 0; j < 4; j++) {
        h[(size_t)(rbase + j) * H_DIM + c] = acc[m][n][j];
      }
    }
  }
}

// ---------------------------------------------------------------------------
// Router v2 (MFMA, R14-verified): 16 tokens/block, 256 thr (4 waves).
// ---------------------------------------------------------------------------
__device__ __forceinline__ float gelu_exact(float v) {
  return 0.5f * v * (1.0f + erff(v * 0.70710678118654752f));
}

__global__ __launch_bounds__(256) void router_kernel(
    const float* __restrict__ hbuf, const float* __restrict__ b1,
    const float* __restrict__ gamma, const float* __restrict__ beta,
    const _Float16* __restrict__ pW2h, const _Float16* __restrict__ pW2l,
    const float* __restrict__ b2, float* __restrict__ out) {
  extern __shared__ __align__(16) char rsm[];
  char* gh = rsm;                    // 32KB
  char* gl = rsm + 32768;            // 32KB
  float* lg = (float*)(rsm + 65536); // 16 x 64 fp32 = 4KB

  const int t = threadIdx.x;
  const int tok0 = blockIdx.x * 16;

  const int tk = t >> 4;
  const int l16 = t & 15;
  {
    const float* hr = hbuf + (size_t)(tok0 + tk) * H_DIM;
    float vals[64];
    float s = 0.f, s2 = 0.f;
#pragma unroll
    for (int q2 = 0; q2 < 8; q2++) {
      const int j = q2 * 128 + l16 * 8;
      float4 v0 = *(const float4*)(hr + j);
      float4 v1 = *(const float4*)(hr + j + 4);
      float4 b0 = *(const float4*)(b1 + j);
      float4 b1v = *(const float4*)(b1 + j + 4);
      v0.x += b0.x; v0.y += b0.y; v0.z += b0.z; v0.w += b0.w;
      v1.x += b1v.x; v1.y += b1v.y; v1.z += b1v.z; v1.w += b1v.w;
      vals[q2 * 8 + 0] = v0.x; vals[q2 * 8 + 1] = v0.y;
      vals[q2 * 8 + 2] = v0.z; vals[q2 * 8 + 3] = v0.w;
      vals[q2 * 8 + 4] = v1.x; vals[q2 * 8 + 5] = v1.y;
      vals[q2 * 8 + 6] = v1.z; vals[q2 * 8 + 7] = v1.w;
      s += v0.x + v0.y + v0.z + v0.w + v1.x + v1.y + v1.z + v1.w;
      s2 += v0.x * v0.x + v0.y * v0.y + v0.z * v0.z + v0.w * v0.w +
            v1.x * v1.x + v1.y * v1.y + v1.z * v1.z + v1.w * v1.w;
    }
#pragma unroll
    for (int off = 8; off; off >>= 1) {
      s += __shfl_xor(s, off, 16);
      s2 += __shfl_xor(s2, off, 16);
    }
    const float mean = s * (1.f / 1024.f);
    const float var = s2 * (1.f / 1024.f) - mean * mean;
    const float rstd = rsqrtf(var + 1e-5f);
    const int swz = ((tk >> 1) & 3);
#pragma unroll
    for (int q2 = 0; q2 < 8; q2++) {
      const int j = q2 * 128 + l16 * 8;
      half8 hh, ll;
#pragma unroll
      for (int e = 0; e < 8; e++) {
        const int jj = q2 * 8 + e;
        const int col = j + e;
        const float gm = gamma[col], bt = beta[col];
        const float gv = gelu_exact((vals[jj] - mean) * rstd * gm + bt);
        const _Float16 hv = (_Float16)gv;
        hh[e] = hv;
        ll[e] = (_Float16)(gv - (float)hv);
      }
      const int sidx = q2 * 4 + (l16 >> 2);
      const int addr = sidx * 1024 + tk * 64 + (((l16 & 3) ^ swz) << 4);
      *(half8*)(gh + addr) = hh;
      *(half8*)(gl + addr) = ll;
    }
  }
  __syncthreads();

  const int wave = t >> 6;
  const int lane = t & 63;
  const int kg = lane >> 4;
  const int fr = lane & 15;
  {
    floatx4 acc = (floatx4){0.f, 0.f, 0.f, 0.f};
    const int aswz = ((fr >> 1) & 3);
#pragma unroll
    for (int s = 0; s < 32; s++) {
      const int aaddr = s * 1024 + fr * 64 + ((kg ^ aswz) << 4);
      half8 ah = *(const half8*)(gh + aaddr);
      half8 al = *(const half8*)(gl + aaddr);
      const size_t bo = (((size_t)s * 4 + wave) * 64 + lane) * 8;
      half8 bh = *(const half8*)(pW2h + bo);
      half8 bl = *(const half8*)(pW2l + bo);
      acc = __builtin_amdgcn_mfma_f32_16x16x32_f16(ah, bh, acc, 0, 0, 0);
      acc = __builtin_amdgcn_mfma_f32_16x16x32_f16(ah, bl, acc, 0, 0, 0);
      acc = __builtin_amdgcn_mfma_f32_16x16x32_f16(al, bh, acc, 0, 0, 0);
    }
#pragma unroll
    for (int j = 0; j < 4; j++) {
      lg[(kg * 4 + j) * E_DIM + wave * 16 + fr] = acc[j];
    }
  }
  __syncthreads();

  float* out_idx = out;
  float* out_w = out + 32768;
  float* out_logits = out + 65536;

  const float b2v = b2[lane];
#pragma unroll
  for (int tt = 0; tt < 4; tt++) {
    const int tok = wave * 4 + tt;
    const int n = tok0 + tok;
    const float L = lg[tok * E_DIM + lane] + b2v;
    float m = L;
#pragma unroll
    for (int off = 32; off; off >>= 1) m = fmaxf(m, __shfl_xor(m, off));
    const float ex = expf(L - m);
    float sum = ex;
#pragma unroll
    for (int off = 32; off; off >>= 1) sum += __shfl_xor(sum, off);

    float v1 = L; int i1 = lane;
#pragma unroll
    for (int off = 32; off; off >>= 1) {
      float ov = __shfl_xor(v1, off);
      int oi = __shfl_xor(i1, off);
      if (ov > v1 || (ov == v1 && oi < i1)) { v1 = ov; i1 = oi; }
    }
    float v2 = (lane == i1) ? -1e30f : L; int i2 = lane;
#pragma unroll
    for (int off = 32; off; off >>= 1) {
      float ov = __shfl_xor(v2, off);
      int oi = __shfl_xor(i2, off);
      if (ov > v2 || (ov == v2 && oi < i2)) { v2 = ov; i2 = oi; }
    }

    out_logits[(size_t)n * 64 + lane] = L;
    if (lane == 0) {
      const float p1 = expf(v1 - m) / sum;
      const float p2 = expf(v2 - m) / sum;
      const float dn = p1 + p2 + 1e-9f;
      out_idx[n * 2 + 0] = (float)i1;
      out_idx[n * 2 + 1] = (float)i2;
      out_w[n * 2 + 0] = p1 / dn;
      out_w[n * 2 + 1] = p2 / dn;
    }
  }
}

extern "C" void kernel_launch(void* const* d_in, const int* in_sizes, int n_in,
                              void* d_out, int out_size, void* d_ws, size_t ws_size,
                              hipStream_t stream) {
  const float* x = (const float*)d_in[0];
  const float* W1 = (const float*)d_in[1];
  const float* b1 = (const float*)d_in[2];
  const float* gamma = (const float*)d_in[3];
  const float* beta = (const float*)d_in[4];
  const float* W2 = (const float*)d_in[5];
  const float* b2 = (const float*)d_in[6];
  float* out = (float*)d_out;

  char* ws = (char*)d_ws;
  _Float16* whT = (_Float16*)ws;                  // 4 MiB
  _Float16* wlT = (_Float16*)(ws + 4194304);      // 4 MiB
  float* hbuf = (float*)(ws + 8388608);           // 64 MiB
  _Float16* pW2h = (_Float16*)(ws + 75497472);    // 128 KiB
  _Float16* pW2l = (_Float16*)(ws + 75628544);    // 128 KiB

  (void)hipFuncSetAttribute((const void*)gemm1_mfma_kernel,
                            hipFuncAttributeMaxDynamicSharedMemorySize,
                            131072);
  (void)hipFuncSetAttribute((const void*)router_kernel,
                            hipFuncAttributeMaxDynamicSharedMemorySize,
                            69632);

  splitT_w1_kernel<<<dim3(D_DIM / 64, H_DIM / 64), 256, 0, stream>>>(W1, whT, wlT);
  pack_w2_kernel<<<32, 256, 0, stream>>>(W2, pW2h, pW2l);

  gemm1_mfma_kernel<<<256, 1024, 131072, stream>>>(x, whT, wlT, hbuf);

  router_kernel<<<N_TOK / 16, 256, 69632, stream>>>(hbuf, b1, gamma, beta,
                                                    pW2h, pW2l, b2, out);
}

// Round 17
// 219.350 us; speedup vs baseline: 1.3194x; 1.2107x over previous
//
#include <hip/hip_runtime.h>
#include <hip/hip_bf16.h>
#include <cmath>

#define N_TOK 16384
#define D_DIM 2048
#define H_DIM 1024
#define E_DIM 64

typedef _Float16 half8 __attribute__((ext_vector_type(8)));
typedef float floatx4 __attribute__((ext_vector_type(4)));

#define GLOAD_LDS(gp, lp)                                                      \
  __builtin_amdgcn_global_load_lds(                                            \
      (const __attribute__((address_space(1))) unsigned int*)(gp),             \
      (__attribute__((address_space(3))) unsigned int*)(lp), 16, 0, 0)

// ---------------------------------------------------------------------------
// Transpose + split W1 [2048k][1024c] -> whT/wlT [1024c][2048k] f16.
// ---------------------------------------------------------------------------
__global__ __launch_bounds__(256) void splitT_w1_kernel(
    const float* __restrict__ W1, _Float16* __restrict__ whT,
    _Float16* __restrict__ wlT) {
  __shared__ float ls[64][65];
  const int k0 = blockIdx.x * 64;
  const int c0 = blockIdx.y * 64;
  const int t = threadIdx.x;
  const int tr = t >> 6;
  const int tc = t & 63;
#pragma unroll
  for (int i = 0; i < 16; i++) {
    int k = tr * 16 + i;
    ls[k][tc] = W1[(size_t)(k0 + k) * H_DIM + c0 + tc];
  }
  __syncthreads();
#pragma unroll
  for (int i = 0; i < 16; i++) {
    int c = tr * 16 + i;
    float v = ls[tc][c];
    _Float16 hv = (_Float16)v;
    _Float16 lv = (_Float16)(v - (float)hv);
    whT[(size_t)(c0 + c) * D_DIM + k0 + tc] = hv;
    wlT[(size_t)(c0 + c) * D_DIM + k0 + tc] = lv;
  }
}

// ---------------------------------------------------------------------------
// Pack + split W2 [1024k][64e] -> MFMA-B-fragment-order hi/lo f16.
// ---------------------------------------------------------------------------
__global__ __launch_bounds__(256) void pack_w2_kernel(
    const float* __restrict__ W2, _Float16* __restrict__ pW2h,
    _Float16* __restrict__ pW2l) {
  const int s = blockIdx.x;  // 32 ksteps
  const int ng = threadIdx.x >> 6;
  const int lane = threadIdx.x & 63;
  const int kg = lane >> 4, fr = lane & 15;
  half8 hh, ll;
#pragma unroll
  for (int j = 0; j < 8; j++) {
    const float v = W2[(size_t)(s * 32 + kg * 8 + j) * E_DIM + ng * 16 + fr];
    const _Float16 hv = (_Float16)v;
    hh[j] = hv;
    ll[j] = (_Float16)(v - (float)hv);
  }
  const size_t idx = (((size_t)s * 4 + ng) * 64 + lane) * 8;
  *(half8*)(pW2h + idx) = hh;
  *(half8*)(pW2l + idx) = ll;
}

// ---------------------------------------------------------------------------
// GEMM1 (R16-verified, verbatim): 256x256 tile, BK=32, 1024 thr (16 waves,
// 4x4 grid, wave tile 64x64), counted-vmcnt 2-barrier pipeline.
// ---------------------------------------------------------------------------
__global__ __launch_bounds__(1024, 4) void gemm1_mfma_kernel(
    const float* __restrict__ x, const _Float16* __restrict__ whT,
    const _Float16* __restrict__ wlT, float* __restrict__ h) {
  extern __shared__ __align__(16) char smem[];  // 2 x 64KB: Ah|Al|Bh|Bl

  const int t = threadIdx.x;
  const int wave = t >> 6;
  const int lane = t & 63;

  const int bid = blockIdx.x;
  const int swz = (bid & 7) * 32 + (bid >> 3);
  const int by = swz >> 2, bx = swz & 3;
  const int row0 = by * 256, col0 = bx * 256;
  const int wr = wave >> 2, wc = wave & 3;

  floatx4 acc[4][4];
#pragma unroll
  for (int m = 0; m < 4; m++)
#pragma unroll
    for (int n = 0; n < 4; n++) acc[m][n] = (floatx4){0.f, 0.f, 0.f, 0.f};

  const int arow = t >> 2;
  const int aslot = t & 3;
  const int awaddr = arow * 64 + ((aslot ^ ((arow >> 1) & 3)) << 4);
  const size_t gaoff = (size_t)(row0 + arow) * D_DIM + aslot * 8;

  const int bo_ = t * 16;
  const int brow = bo_ >> 6;
  const int bss = ((bo_ >> 4) & 3) ^ ((brow >> 1) & 3);
  const int ldsBoff = wave * 1024;
  const size_t gboff = (size_t)(col0 + brow) * D_DIM + bss * 8;

  const int kg = lane >> 4;
  const int fr = lane & 15;

  int afr[4], bfr[4];
#pragma unroll
  for (int m = 0; m < 4; m++) {
    const int r = wr * 64 + m * 16 + fr;
    afr[m] = r * 64 + ((kg ^ ((r >> 1) & 3)) << 4);
  }
#pragma unroll
  for (int n = 0; n < 4; n++) {
    const int c = wc * 64 + n * 16 + fr;
    bfr[n] = c * 64 + ((kg ^ ((c >> 1) & 3)) << 4);
  }

  float4 av0, av1;

#define LOAD_A(T)                                                              \
  do {                                                                         \
    const float* pa = x + gaoff + (size_t)(T) * 32;                            \
    av0 = *(const float4*)pa;                                                  \
    av1 = *(const float4*)(pa + 4);                                            \
  } while (0)

#define WRITE_A(B)                                                             \
  do {                                                                         \
    char* lb = smem + (B) * 65536;                                             \
    float vs[8] = {av0.x, av0.y, av0.z, av0.w, av1.x, av1.y, av1.z, av1.w};    \
    half8 hh, ll;                                                              \
    _Pragma("unroll") for (int j = 0; j < 8; j++) {                            \
      _Float16 hv = (_Float16)vs[j];                                           \
      hh[j] = hv;                                                              \
      ll[j] = (_Float16)(vs[j] - (float)hv);                                   \
    }                                                                          \
    *(half8*)(lb + awaddr) = hh;                                               \
    *(half8*)(lb + 16384 + awaddr) = ll;                                       \
  } while (0)

#define GLD_B(T)                                                               \
  do {                                                                         \
    const size_t kk = (size_t)(T) * 32;                                        \
    char* db = smem + ((T) & 1) * 65536;                                       \
    GLOAD_LDS(whT + gboff + kk, db + 32768 + ldsBoff);                         \
    GLOAD_LDS(wlT + gboff + kk, db + 49152 + ldsBoff);                         \
  } while (0)

#define BODY(T, STG)                                                           \
  do {                                                                         \
    const char* cb = smem + ((T) & 1) * 65536;                                 \
    if ((STG) < 2) GLD_B((T) + 1);                                             \
    __builtin_amdgcn_sched_barrier(0);                                         \
    half8 bh[4], bl[4];                                                        \
    _Pragma("unroll") for (int n = 0; n < 4; n++) {                            \
      bh[n] = *(const half8*)(cb + 32768 + bfr[n]);                            \
      bl[n] = *(const half8*)(cb + 49152 + bfr[n]);                            \
    }                                                                          \
    _Pragma("unroll") for (int m = 0; m < 4; m++) {                            \
      half8 ah = *(const half8*)(cb + afr[m]);                                 \
      half8 al = *(const half8*)(cb + 16384 + afr[m]);                         \
      __builtin_amdgcn_s_setprio(1);                                           \
      _Pragma("unroll") for (int n = 0; n < 4; n++) {                          \
        acc[m][n] = __builtin_amdgcn_mfma_f32_16x16x32_f16(ah, bh[n],          \
                                                           acc[m][n], 0, 0, 0);\
        acc[m][n] = __builtin_amdgcn_mfma_f32_16x16x32_f16(ah, bl[n],          \
                                                           acc[m][n], 0, 0, 0);\
        acc[m][n] = __builtin_amdgcn_mfma_f32_16x16x32_f16(al, bh[n],          \
                                                           acc[m][n], 0, 0, 0);\
      }                                                                        \
      __builtin_amdgcn_s_setprio(0);                                           \
    }                                                                          \
    __builtin_amdgcn_sched_barrier(0);                                         \
    if ((STG) < 2) {                                                           \
      WRITE_A(((T) + 1) & 1);                                                  \
      if ((STG) == 0) {                                                        \
        LOAD_A((T) + 2);                                                       \
        __builtin_amdgcn_sched_barrier(0);                                     \
        asm volatile("s_waitcnt vmcnt(2)" ::: "memory");                       \
      } else {                                                                 \
        __builtin_amdgcn_sched_barrier(0);                                     \
        asm volatile("s_waitcnt vmcnt(0)" ::: "memory");                       \
      }                                                                        \
      asm volatile("s_waitcnt lgkmcnt(0)" ::: "memory");                       \
      __builtin_amdgcn_s_barrier();                                            \
      __builtin_amdgcn_sched_barrier(0);                                       \
    }                                                                          \
  } while (0)

  LOAD_A(0);
  GLD_B(0);
  WRITE_A(0);
  LOAD_A(1);
  asm volatile("s_waitcnt vmcnt(2)" ::: "memory");
  asm volatile("s_waitcnt lgkmcnt(0)" ::: "memory");
  __builtin_amdgcn_s_barrier();
  __builtin_amdgcn_sched_barrier(0);

#pragma unroll 1
  for (int T = 0; T < 62; ++T) {
    BODY(T, 0);
  }
  BODY(62, 1);
  BODY(63, 2);

#undef LOAD_A
#undef WRITE_A
#undef GLD_B
#undef BODY

  const int rj = (lane >> 4) * 4;
#pragma unroll
  for (int m = 0; m < 4; m++) {
    const int rbase = row0 + wr * 64 + m * 16 + rj;
#pragma unroll
    for (int n = 0; n < 4; n++) {
      const int c = col0 + wc * 64 + n * 16 + fr;
#pragma unroll
      for (int j = 0; j < 4; j++) {
        h[(size_t)(rbase + j) * H_DIM + c] = acc[m][n][j];
      }
    }
  }
}

// ---------------------------------------------------------------------------
// Router v3 (MFMA): 8 tokens/block, 2048 blocks, 256 thr (4 waves).
// LDS = gh 16K | gl 16K | lg 2K = 34KB -> 4 blocks/CU (vs v2's 2).
// Phase 1: LN+GELU, 32 lanes/token, float4 gamma/beta loads; g hi/lo into
//   32 chunks of [8 tok][64B] (slot ^ ((tok>>1)&3) swizzle).
// Phase 2: 16x16x32 MFMA; A-lanes fr>=8 read aliased garbage rows (safe:
//   MFMA rows independent; lg write gated kg<2). B from packed pW2 (L2).
// Phase 3: +b2, softmax, top-2 (lower-index tie-break), 2 tokens/wave.
// ---------------------------------------------------------------------------
__device__ __forceinline__ float gelu_exact(float v) {
  return 0.5f * v * (1.0f + erff(v * 0.70710678118654752f));
}

__global__ __launch_bounds__(256) void router_kernel(
    const float* __restrict__ hbuf, const float* __restrict__ b1,
    const float* __restrict__ gamma, const float* __restrict__ beta,
    const _Float16* __restrict__ pW2h, const _Float16* __restrict__ pW2l,
    const float* __restrict__ b2, float* __restrict__ out) {
  extern __shared__ __align__(16) char rsm[];
  char* gh = rsm;                    // 16KB: 32 chunks x [8 tok][64B]
  char* gl = rsm + 16384;            // 16KB
  float* lg = (float*)(rsm + 32768); // 8 x 64 fp32 = 2KB

  const int t = threadIdx.x;
  const int tok0 = blockIdx.x * 8;

  // ---- Phase 1: LN + GELU, 32 lanes per token, 8-elem units ----
  const int tk = t >> 5;    // token 0..7
  const int l32 = t & 31;
  {
    const float* hr = hbuf + (size_t)(tok0 + tk) * H_DIM;
    float vals[32];
    float s = 0.f, s2 = 0.f;
#pragma unroll
    for (int q = 0; q < 4; q++) {
      const int j = q * 256 + l32 * 8;
      float4 v0 = *(const float4*)(hr + j);
      float4 v1 = *(const float4*)(hr + j + 4);
      float4 b0 = *(const float4*)(b1 + j);
      float4 b1v = *(const float4*)(b1 + j + 4);
      v0.x += b0.x; v0.y += b0.y; v0.z += b0.z; v0.w += b0.w;
      v1.x += b1v.x; v1.y += b1v.y; v1.z += b1v.z; v1.w += b1v.w;
      vals[q * 8 + 0] = v0.x; vals[q * 8 + 1] = v0.y;
      vals[q * 8 + 2] = v0.z; vals[q * 8 + 3] = v0.w;
      vals[q * 8 + 4] = v1.x; vals[q * 8 + 5] = v1.y;
      vals[q * 8 + 6] = v1.z; vals[q * 8 + 7] = v1.w;
      s += v0.x + v0.y + v0.z + v0.w + v1.x + v1.y + v1.z + v1.w;
      s2 += v0.x * v0.x + v0.y * v0.y + v0.z * v0.z + v0.w * v0.w +
            v1.x * v1.x + v1.y * v1.y + v1.z * v1.z + v1.w * v1.w;
    }
#pragma unroll
    for (int off = 16; off; off >>= 1) {
      s += __shfl_xor(s, off, 32);
      s2 += __shfl_xor(s2, off, 32);
    }
    const float mean = s * (1.f / 1024.f);
    const float var = s2 * (1.f / 1024.f) - mean * mean;
    const float rstd = rsqrtf(var + 1e-5f);
    const int swz = (tk >> 1) & 3;
#pragma unroll
    for (int q = 0; q < 4; q++) {
      const int j = q * 256 + l32 * 8;
      float4 gm0 = *(const float4*)(gamma + j);
      float4 gm1 = *(const float4*)(gamma + j + 4);
      float4 bt0 = *(const float4*)(beta + j);
      float4 bt1 = *(const float4*)(beta + j + 4);
      float gms[8] = {gm0.x, gm0.y, gm0.z, gm0.w, gm1.x, gm1.y, gm1.z, gm1.w};
      float bts[8] = {bt0.x, bt0.y, bt0.z, bt0.w, bt1.x, bt1.y, bt1.z, bt1.w};
      half8 hh, ll;
#pragma unroll
      for (int e = 0; e < 8; e++) {
        const float gv =
            gelu_exact((vals[q * 8 + e] - mean) * rstd * gms[e] + bts[e]);
        const _Float16 hv = (_Float16)gv;
        hh[e] = hv;
        ll[e] = (_Float16)(gv - (float)hv);
      }
      const int sidx = q * 8 + (l32 >> 2);            // chunk = k/32
      const int addr = sidx * 512 + tk * 64 + (((l32 & 3) ^ swz) << 4);
      *(half8*)(gh + addr) = hh;
      *(half8*)(gl + addr) = ll;
    }
  }
  __syncthreads();

  // ---- Phase 2: logits via MFMA. wave w -> experts w*16..w*16+15 ----
  const int wave = t >> 6;
  const int lane = t & 63;
  const int kg = lane >> 4;
  const int fr = lane & 15;
  {
    floatx4 acc = (floatx4){0.f, 0.f, 0.f, 0.f};
    const int aswz = (fr >> 1) & 3;  // valid for fr<8; fr>=8 garbage (unused)
#pragma unroll
    for (int s = 0; s < 32; s++) {
      const int aaddr = s * 512 + fr * 64 + ((kg ^ aswz) << 4);
      half8 ah = *(const half8*)(gh + aaddr);
      half8 al = *(const half8*)(gl + aaddr);
      const size_t bo = (((size_t)s * 4 + wave) * 64 + lane) * 8;
      half8 bh = *(const half8*)(pW2h + bo);
      half8 bl = *(const half8*)(pW2l + bo);
      acc = __builtin_amdgcn_mfma_f32_16x16x32_f16(ah, bh, acc, 0, 0, 0);
      acc = __builtin_amdgcn_mfma_f32_16x16x32_f16(ah, bl, acc, 0, 0, 0);
      acc = __builtin_amdgcn_mfma_f32_16x16x32_f16(al, bh, acc, 0, 0, 0);
    }
    // C layout: row(token) = kg*4+j (valid < 8 -> kg<2), col = fr
    if (kg < 2) {
#pragma unroll
      for (int j = 0; j < 4; j++) {
        lg[(kg * 4 + j) * E_DIM + wave * 16 + fr] = acc[j];
      }
    }
  }
  __syncthreads();

  // ---- Phase 3: +b2, softmax, top-2. wave w -> tokens 2w, 2w+1 ----
  float* out_idx = out;
  float* out_w = out + 32768;
  float* out_logits = out + 65536;

  const float b2v = b2[lane];
#pragma unroll
  for (int tt = 0; tt < 2; tt++) {
    const int tok = wave * 2 + tt;
    const int n = tok0 + tok;
    const float L = lg[tok * E_DIM + lane] + b2v;
    float m = L;
#pragma unroll
    for (int off = 32; off; off >>= 1) m = fmaxf(m, __shfl_xor(m, off));
    const float ex = expf(L - m);
    float sum = ex;
#pragma unroll
    for (int off = 32; off; off >>= 1) sum += __shfl_xor(sum, off);

    float v1 = L; int i1 = lane;
#pragma unroll
    for (int off = 32; off; off >>= 1) {
      float ov = __shfl_xor(v1, off);
      int oi = __shfl_xor(i1, off);
      if (ov > v1 || (ov == v1 && oi < i1)) { v1 = ov; i1 = oi; }
    }
    float v2 = (lane == i1) ? -1e30f : L; int i2 = lane;
#pragma unroll
    for (int off = 32; off; off >>= 1) {
      float ov = __shfl_xor(v2, off);
      int oi = __shfl_xor(i2, off);
      if (ov > v2 || (ov == v2 && oi < i2)) { v2 = ov; i2 = oi; }
    }

    out_logits[(size_t)n * 64 + lane] = L;
    if (lane == 0) {
      const float p1 = expf(v1 - m) / sum;
      const float p2 = expf(v2 - m) / sum;
      const float dn = p1 + p2 + 1e-9f;
      out_idx[n * 2 + 0] = (float)i1;
      out_idx[n * 2 + 1] = (float)i2;
      out_w[n * 2 + 0] = p1 / dn;
      out_w[n * 2 + 1] = p2 / dn;
    }
  }
}

extern "C" void kernel_launch(void* const* d_in, const int* in_sizes, int n_in,
                              void* d_out, int out_size, void* d_ws, size_t ws_size,
                              hipStream_t stream) {
  const float* x = (const float*)d_in[0];
  const float* W1 = (const float*)d_in[1];
  const float* b1 = (const float*)d_in[2];
  const float* gamma = (const float*)d_in[3];
  const float* beta = (const float*)d_in[4];
  const float* W2 = (const float*)d_in[5];
  const float* b2 = (const float*)d_in[6];
  float* out = (float*)d_out;

  char* ws = (char*)d_ws;
  _Float16* whT = (_Float16*)ws;                  // 4 MiB
  _Float16* wlT = (_Float16*)(ws + 4194304);      // 4 MiB
  float* hbuf = (float*)(ws + 8388608);           // 64 MiB
  _Float16* pW2h = (_Float16*)(ws + 75497472);    // 128 KiB
  _Float16* pW2l = (_Float16*)(ws + 75628544);    // 128 KiB

  (void)hipFuncSetAttribute((const void*)gemm1_mfma_kernel,
                            hipFuncAttributeMaxDynamicSharedMemorySize,
                            131072);
  (void)hipFuncSetAttribute((const void*)router_kernel,
                            hipFuncAttributeMaxDynamicSharedMemorySize,
                            34816);

  splitT_w1_kernel<<<dim3(D_DIM / 64, H_DIM / 64), 256, 0, stream>>>(W1, whT, wlT);
  pack_w2_kernel<<<32, 256, 0, stream>>>(W2, pW2h, pW2l);

  gemm1_mfma_kernel<<<256, 1024, 131072, stream>>>(x, whT, wlT, hbuf);

  router_kernel<<<N_TOK / 8, 256, 34816, stream>>>(hbuf, b1, gamma, beta,
                                                   pW2h, pW2l, b2, out);
}